// Round 10
// baseline (436.185 us; speedup 1.0000x reference)
//
#include <hip/hip_runtime.h>
#include <hip/hip_fp16.h>

#define NN 50000
#define NE 800000

typedef _Float16 half4v __attribute__((ext_vector_type(4)));
typedef _Float16 half8v __attribute__((ext_vector_type(8)));
typedef float f32x4 __attribute__((ext_vector_type(4)));

static __device__ __forceinline__ float lrelu(float x) { return x > 0.f ? x : 0.2f * x; }

// ---------------- edge-index dtype detection (int32 vs int64) ----------------
__global__ void detect_i64_kernel(const unsigned* __restrict__ ei, int* __restrict__ flag) {
  if (threadIdx.x == 0 && blockIdx.x == 0) {
    int is64 = 1;
    for (int i = 0; i < 64; ++i)
      if (ei[2 * i + 1] != 0u) { is64 = 0; break; }
    *flag = is64;
  }
}

static __device__ __forceinline__ int edge_at(const void* ei, int is64, long long idx) {
  if (is64) return (int)((const long long*)ei)[idx];
  return ((const int*)ei)[idx];
}

// ---------------- CSR build ----------------
__global__ void count_kernel(const void* __restrict__ ei, const int* __restrict__ flag,
                             int* __restrict__ counts) {
  int e = blockIdx.x * blockDim.x + threadIdx.x;
  if (e >= NE) return;
  int is64 = *flag;
  int d = edge_at(ei, is64, (long long)NE + e);
  atomicAdd(&counts[d], 1);
}

// two-level scan: 196 blocks x 256
static __device__ __forceinline__ int block_scan_inc(int v, int tid) {
  __shared__ int ws[4];
  const int lane = tid & 63, wv = tid >> 6;
  #pragma unroll
  for (int off = 1; off < 64; off <<= 1) {
    int t = __shfl_up(v, off);
    if (lane >= off) v += t;
  }
  if (lane == 63) ws[wv] = v;
  __syncthreads();
  int add = 0;
  #pragma unroll
  for (int j = 0; j < 4; ++j) if (j < wv) add += ws[j];
  return v + add;
}

__global__ void scan1_kernel(const int* __restrict__ counts, int* __restrict__ bsums) {
  __shared__ int ws[4];
  const int tid = threadIdx.x;
  const int lane = tid & 63, wv = tid >> 6;
  int i = blockIdx.x * 256 + tid;
  int v = (i < NN) ? counts[i] : 0;
  #pragma unroll
  for (int off = 1; off < 64; off <<= 1) v += __shfl_xor(v, off);
  if (lane == 0) ws[wv] = v;
  __syncthreads();
  if (tid == 0) bsums[blockIdx.x] = ws[0] + ws[1] + ws[2] + ws[3];
}

__global__ void scan2_kernel(int* __restrict__ bsums, int nb) {
  const int tid = threadIdx.x;
  int v = (tid < nb) ? bsums[tid] : 0;
  int inc = block_scan_inc(v, tid);
  if (tid < nb) bsums[tid] = inc - v;   // exclusive
}

__global__ void scan3_kernel(const int* __restrict__ counts, const int* __restrict__ bsums,
                             int* __restrict__ rs) {
  const int tid = threadIdx.x;
  int i = blockIdx.x * 256 + tid;
  int v = (i < NN) ? counts[i] : 0;
  int inc = block_scan_inc(v, tid);
  if (i < NN) rs[i + 1] = bsums[blockIdx.x] + inc;
  if (i == 0) rs[0] = 0;
}

__global__ void scatter_kernel(const void* __restrict__ ei, const int* __restrict__ flag,
                               const int* __restrict__ rs, int* __restrict__ cursor,
                               int* __restrict__ ssrc) {
  int e = blockIdx.x * blockDim.x + threadIdx.x;
  if (e >= NE) return;
  int is64 = *flag;
  int s = edge_at(ei, is64, e);
  int d = edge_at(ei, is64, (long long)NE + e);
  int p = atomicAdd(&cursor[d], 1);
  ssrc[rs[d] + p] = s;
}

// ---------------- fused weight prep: W1t, W2t, Wa1, Wa2 ----------------------
__global__ void prep_kernel(const float* __restrict__ W1, const float* __restrict__ W2,
                            const float* __restrict__ aS1, const float* __restrict__ aD1,
                            const float* __restrict__ aS2, const float* __restrict__ aD2,
                            _Float16* __restrict__ W1t, _Float16* __restrict__ W2t,
                            _Float16* __restrict__ Wa1, _Float16* __restrict__ Wa2) {
  int i = blockIdx.x * blockDim.x + threadIdx.x;
  if (i < 65536) {
    int n = i >> 8, k = i & 255;
    W1t[i] = (_Float16)W1[(size_t)k * 256 + n];
  } else if (i < 98304) {
    int j = i - 65536;
    int n = j >> 8, k = j & 255;
    W2t[j] = (_Float16)W2[(size_t)k * 128 + n];
  } else if (i < 102400) {
    int j = i - 98304;
    int row = j >> 8, k = j & 255;
    int head = row & 7;
    const float* a = (row < 8) ? aS1 : aD1;
    float s = 0.f;
    #pragma unroll 8
    for (int c = 0; c < 32; ++c)
      s += W1[(size_t)k * 256 + head * 32 + c] * a[head * 32 + c];
    Wa1[j] = (_Float16)s;
  } else if (i < 106496) {
    int j = i - 102400;
    int row = j >> 8, k = j & 255;
    int head = row & 7;
    const float* a = (row < 8) ? aS2 : aD2;
    float s = 0.f;
    #pragma unroll 8
    for (int c = 0; c < 16; ++c)
      s += W2[(size_t)k * 128 + head * 16 + c] * a[head * 16 + c];
    Wa2[j] = (_Float16)s;
  }
}

// ---------------- MFMA fp16 GEMM + fused alpha, head-sliced C output ---------
// C written as hs[head][node][CH] where CH = BN/8 (head = col/CH).
template<int BN, int NCF, bool A_HALF>
__global__ __launch_bounds__(256) void gemm_mfma(const void* __restrict__ Araw,
                                                 const _Float16* __restrict__ Wt,
                                                 const _Float16* __restrict__ Wa,
                                                 __half* __restrict__ hs,
                                                 float* __restrict__ alS,
                                                 float* __restrict__ alD, int M) {
  constexpr int CH = BN / 8;        // channels per head (32 or 16)
  __shared__ _Float16 As[64][256 + 8];
  const int tid = threadIdx.x;
  const int bm0 = blockIdx.x * 64;
  if (A_HALF) {
    const _Float16* A = (const _Float16*)Araw;
    for (int idx = tid; idx < 64 * 32; idx += 256) {
      int r = idx >> 5, c8 = (idx & 31) << 3;
      int gr = bm0 + r;
      half8v v = {};
      if (gr < M) v = *(const half8v*)&A[(size_t)gr * 256 + c8];
      *(half8v*)&As[r][c8] = v;
    }
  } else {
    const float* A = (const float*)Araw;
    for (int idx = tid; idx < 64 * 64; idx += 256) {
      int r = idx >> 6, c4 = (idx & 63) << 2;
      int gr = bm0 + r;
      float4 v = make_float4(0.f, 0.f, 0.f, 0.f);
      if (gr < M) v = *(const float4*)&A[(size_t)gr * 256 + c4];
      half4v h = { (_Float16)v.x, (_Float16)v.y, (_Float16)v.z, (_Float16)v.w };
      *(half4v*)&As[r][c4] = h;
    }
  }
  __syncthreads();
  const int lane = tid & 63, wv = tid >> 6;
  const int ncol0 = wv * (16 * NCF);
  const int lrow = lane & 15, lk8 = (lane >> 4) << 3;
  f32x4 acc[4][NCF];
  f32x4 acca[4];
  #pragma unroll
  for (int rf = 0; rf < 4; ++rf) {
    acca[rf] = (f32x4){0.f, 0.f, 0.f, 0.f};
    #pragma unroll
    for (int cf = 0; cf < NCF; ++cf) acc[rf][cf] = (f32x4){0.f, 0.f, 0.f, 0.f};
  }
  #pragma unroll
  for (int k0 = 0; k0 < 256; k0 += 32) {
    const int ks = k0 + lk8;
    half8v af[4];
    #pragma unroll
    for (int rf = 0; rf < 4; ++rf)
      af[rf] = *(const half8v*)&As[16 * rf + lrow][ks];
    #pragma unroll
    for (int cf = 0; cf < NCF; ++cf) {
      half8v bf = *(const half8v*)&Wt[(size_t)(ncol0 + 16 * cf + lrow) * 256 + ks];
      #pragma unroll
      for (int rf = 0; rf < 4; ++rf)
        acc[rf][cf] = __builtin_amdgcn_mfma_f32_16x16x32_f16(af[rf], bf, acc[rf][cf], 0, 0, 0);
    }
    if (wv == 0) {
      half8v bfa = *(const half8v*)&Wa[(size_t)lrow * 256 + ks];
      #pragma unroll
      for (int rf = 0; rf < 4; ++rf)
        acca[rf] = __builtin_amdgcn_mfma_f32_16x16x32_f16(af[rf], bfa, acca[rf], 0, 0, 0);
    }
  }
  #pragma unroll
  for (int rf = 0; rf < 4; ++rf) {
    #pragma unroll
    for (int j = 0; j < 4; ++j) {
      int row = bm0 + 16 * rf + 4 * (lane >> 4) + j;
      if (row < M) {
        #pragma unroll
        for (int cf = 0; cf < NCF; ++cf) {
          int col = ncol0 + 16 * cf + lrow;
          int head = col / CH, ch = col % CH;
          hs[((size_t)head * NN + row) * CH + ch] = __float2half(acc[rf][cf][j]);
        }
      }
    }
  }
  if (wv == 0) {
    #pragma unroll
    for (int rf = 0; rf < 4; ++rf) {
      #pragma unroll
      for (int j = 0; j < 4; ++j) {
        int row = bm0 + 16 * rf + 4 * (lane >> 4) + j;
        if (row < M) {
          float v = acca[rf][j];
          if (lrow < 8) alS[row * 8 + lrow] = v;
          else          alD[row * 8 + (lrow - 8)] = v;
        }
      }
    }
  }
}

// ---------------- layer-1 aggregation, head-sliced ---------------------------
// block: 4 waves = 4 nodes, all same head (head = blockIdx%8 -> XCD affinity).
// wave: 4 groups x 16 lanes; group g handles edges j+g, lane c = channels 2c,2c+1.
__global__ __launch_bounds__(256) void agg1_kernel(const __half* __restrict__ hs, // [8][NN][32]
    const float* __restrict__ as, const float* __restrict__ ad,
    const int* __restrict__ rs, const int* __restrict__ ssrc,
    const float* __restrict__ bias, __half* __restrict__ out /* [NN][256] */) {
  const int head = blockIdx.x & 7;
  const int node = (blockIdx.x >> 3) * 4 + (threadIdx.x >> 6);
  const int lane = threadIdx.x & 63;
  if (node >= NN) return;
  const int g = lane >> 4;
  const int c = lane & 15;
  const int beg = rs[node], end = rs[node + 1];
  const int deg = end - beg;
  const float advh = ad[node * 8 + head];
  const __half* slice = hs + (size_t)head * NN * 32;
  float denom = 0.f;
  float ax = 0.f, ay = 0.f;
  {
    float p = __expf(lrelu(as[node * 8 + head] + advh));   // self loop
    float2 hf = __half22float2(*(const __half2*)&slice[(size_t)node * 32 + 2 * c]);
    if (g == 0) { ax = p * hf.x; ay = p * hf.y; denom = p; }
  }
  for (int base = 0; base < deg; base += 64) {
    const int cnt = min(deg - base, 64);
    int sv = (lane < cnt) ? ssrc[beg + base + lane] : 0;
    int j = 0;
    for (; j + 16 <= cnt; j += 16) {
      int s0 = __shfl(sv, j + g);
      int s1 = __shfl(sv, j + 4 + g);
      int s2 = __shfl(sv, j + 8 + g);
      int s3 = __shfl(sv, j + 12 + g);
      float a0 = as[s0 * 8 + head], a1 = as[s1 * 8 + head];
      float a2 = as[s2 * 8 + head], a3 = as[s3 * 8 + head];
      __half2 h0 = *(const __half2*)&slice[(size_t)s0 * 32 + 2 * c];
      __half2 h1 = *(const __half2*)&slice[(size_t)s1 * 32 + 2 * c];
      __half2 h2 = *(const __half2*)&slice[(size_t)s2 * 32 + 2 * c];
      __half2 h3 = *(const __half2*)&slice[(size_t)s3 * 32 + 2 * c];
      float p0 = __expf(lrelu(a0 + advh)), p1 = __expf(lrelu(a1 + advh));
      float p2 = __expf(lrelu(a2 + advh)), p3 = __expf(lrelu(a3 + advh));
      denom += (p0 + p1) + (p2 + p3);
      float2 f;
      f = __half22float2(h0); ax += p0 * f.x; ay += p0 * f.y;
      f = __half22float2(h1); ax += p1 * f.x; ay += p1 * f.y;
      f = __half22float2(h2); ax += p2 * f.x; ay += p2 * f.y;
      f = __half22float2(h3); ax += p3 * f.x; ay += p3 * f.y;
    }
    for (; j < cnt; j += 4) {
      int idx = j + g;
      int s = __shfl(sv, min(idx, cnt - 1));
      float a0 = as[s * 8 + head];
      __half2 hv = *(const __half2*)&slice[(size_t)s * 32 + 2 * c];
      float p = (idx < cnt) ? __expf(lrelu(a0 + advh)) : 0.f;
      float2 f = __half22float2(hv);
      ax += p * f.x; ay += p * f.y;
      denom += p;
    }
  }
  ax += __shfl_xor(ax, 16); ay += __shfl_xor(ay, 16); denom += __shfl_xor(denom, 16);
  ax += __shfl_xor(ax, 32); ay += __shfl_xor(ay, 32); denom += __shfl_xor(denom, 32);
  const float inv = 1.f / (denom + 1e-16f);
  const int ch = head * 32 + 2 * c;
  float o0 = ax * inv + bias[ch];
  float o1 = ay * inv + bias[ch + 1];
  o0 = o0 > 0.f ? o0 : __expf(o0) - 1.f;
  o1 = o1 > 0.f ? o1 : __expf(o1) - 1.f;
  if (g == 0)
    *(__half2*)&out[(size_t)node * 256 + ch] = __floats2half2_rn(o0, o1);
}

// ---------------- layer-2 aggregation, head-sliced (writes logits) -----------
// wave: 8 groups x 8 lanes; group g handles edges j+g, lane c = channels 2c,2c+1.
__global__ __launch_bounds__(256) void agg2_kernel(const __half* __restrict__ hs, // [8][NN][16]
    const float* __restrict__ as, const float* __restrict__ ad,
    const int* __restrict__ rs, const int* __restrict__ ssrc,
    const float* __restrict__ bias, float* __restrict__ vbuf /* [NN][128] */) {
  const int head = blockIdx.x & 7;
  const int node = (blockIdx.x >> 3) * 4 + (threadIdx.x >> 6);
  const int lane = threadIdx.x & 63;
  if (node >= NN) return;
  const int g = lane >> 3;
  const int c = lane & 7;
  const int beg = rs[node], end = rs[node + 1];
  const int deg = end - beg;
  const float advh = ad[node * 8 + head];
  const __half* slice = hs + (size_t)head * NN * 16;
  float denom = 0.f;
  float ax = 0.f, ay = 0.f;
  {
    float p = __expf(lrelu(as[node * 8 + head] + advh));   // self loop
    float2 hf = __half22float2(*(const __half2*)&slice[(size_t)node * 16 + 2 * c]);
    if (g == 0) { ax = p * hf.x; ay = p * hf.y; denom = p; }
  }
  for (int base = 0; base < deg; base += 64) {
    const int cnt = min(deg - base, 64);
    int sv = (lane < cnt) ? ssrc[beg + base + lane] : 0;
    int j = 0;
    for (; j + 16 <= cnt; j += 16) {
      int s0 = __shfl(sv, j + g);
      int s1 = __shfl(sv, j + 8 + g);
      float a0 = as[s0 * 8 + head], a1 = as[s1 * 8 + head];
      __half2 h0 = *(const __half2*)&slice[(size_t)s0 * 16 + 2 * c];
      __half2 h1 = *(const __half2*)&slice[(size_t)s1 * 16 + 2 * c];
      float p0 = __expf(lrelu(a0 + advh)), p1 = __expf(lrelu(a1 + advh));
      denom += p0 + p1;
      float2 f;
      f = __half22float2(h0); ax += p0 * f.x; ay += p0 * f.y;
      f = __half22float2(h1); ax += p1 * f.x; ay += p1 * f.y;
    }
    for (; j < cnt; j += 8) {
      int idx = j + g;
      int s = __shfl(sv, min(idx, cnt - 1));
      float a0 = as[s * 8 + head];
      __half2 hv = *(const __half2*)&slice[(size_t)s * 16 + 2 * c];
      float p = (idx < cnt) ? __expf(lrelu(a0 + advh)) : 0.f;
      float2 f = __half22float2(hv);
      ax += p * f.x; ay += p * f.y;
      denom += p;
    }
  }
  ax += __shfl_xor(ax, 8);  ay += __shfl_xor(ay, 8);  denom += __shfl_xor(denom, 8);
  ax += __shfl_xor(ax, 16); ay += __shfl_xor(ay, 16); denom += __shfl_xor(denom, 16);
  ax += __shfl_xor(ax, 32); ay += __shfl_xor(ay, 32); denom += __shfl_xor(denom, 32);
  const float inv = 1.f / (denom + 1e-16f);
  const int ch = head * 16 + 2 * c;
  if (g == 0) {
    float2 o = make_float2(ax * inv + bias[ch], ay * inv + bias[ch + 1]);
    *(float2*)&vbuf[(size_t)node * 128 + ch] = o;
  }
}

// ---------------- final log-softmax over 128 channels ------------------------
__global__ __launch_bounds__(256) void logsm_kernel(const float* __restrict__ vbuf,
                                                    float* __restrict__ out) {
  const int node = (blockIdx.x * blockDim.x + threadIdx.x) >> 6;
  const int lane = threadIdx.x & 63;
  if (node >= NN) return;
  float2 v = *(const float2*)&vbuf[(size_t)node * 128 + lane * 2];
  float mx = fmaxf(v.x, v.y);
  #pragma unroll
  for (int off = 1; off < 64; off <<= 1) mx = fmaxf(mx, __shfl_xor(mx, off));
  float sum = __expf(v.x - mx) + __expf(v.y - mx);
  #pragma unroll
  for (int off = 1; off < 64; off <<= 1) sum += __shfl_xor(sum, off);
  float lse = mx + __logf(sum);
  __builtin_nontemporal_store(v.x - lse, &out[(size_t)node * 128 + lane * 2]);
  __builtin_nontemporal_store(v.y - lse, &out[(size_t)node * 128 + lane * 2 + 1]);
}

// ---------------- host ----------------
extern "C" void kernel_launch(void* const* d_in, const int* in_sizes, int n_in,
                              void* d_out, int out_size, void* d_ws, size_t ws_size,
                              hipStream_t stream) {
  const float* x    = (const float*)d_in[0];
  const void*  ei   = d_in[1];
  const float* W1   = (const float*)d_in[2];
  const float* aS1  = (const float*)d_in[3];
  const float* aD1  = (const float*)d_in[4];
  const float* b1   = (const float*)d_in[5];
  const float* W2   = (const float*)d_in[6];
  const float* aS2  = (const float*)d_in[7];
  const float* aD2  = (const float*)d_in[8];
  const float* b2   = (const float*)d_in[9];
  float* out = (float*)d_out;

  char* ws = (char*)d_ws;
  __half* hs1  = (__half*)ws;          ws += (size_t)NN * 256 * 2;  // [8][NN][32] sliced h1 / h2([8][NN][16])
  __half* hmid = (__half*)ws;          ws += (size_t)NN * 256 * 2;  // ELU(agg1) row-major
  float* vbuf  = (float*)ws;           ws += (size_t)NN * 128 * 4;  // layer-2 logits
  _Float16* W1t = (_Float16*)ws;       ws += (size_t)256 * 256 * 2;
  _Float16* W2t = (_Float16*)ws;       ws += (size_t)128 * 256 * 2;
  _Float16* Wa1 = (_Float16*)ws;       ws += (size_t)16 * 256 * 2;
  _Float16* Wa2 = (_Float16*)ws;       ws += (size_t)16 * 256 * 2;
  float* alS  = (float*)ws;            ws += (size_t)NN * 8 * 4;
  float* alD  = (float*)ws;            ws += (size_t)NN * 8 * 4;
  int* counts = (int*)ws;              ws += (size_t)NN * 4;
  int* rs     = (int*)ws;              ws += (size_t)(NN + 1) * 4;
  int* bsums  = (int*)ws;              ws += (size_t)256 * 4;
  int* ssrc   = (int*)ws;              ws += (size_t)NE * 4;
  int* flag   = (int*)ws;              ws += 256;

  const int NB = (NN + 255) / 256;

  // ---- CSR build ----
  detect_i64_kernel<<<1, 64, 0, stream>>>((const unsigned*)ei, flag);
  hipMemsetAsync(counts, 0, (size_t)NN * 4, stream);
  count_kernel<<<(NE + 255) / 256, 256, 0, stream>>>(ei, flag, counts);
  scan1_kernel<<<NB, 256, 0, stream>>>(counts, bsums);
  scan2_kernel<<<1, 256, 0, stream>>>(bsums, NB);
  scan3_kernel<<<NB, 256, 0, stream>>>(counts, bsums, rs);
  hipMemsetAsync(counts, 0, (size_t)NN * 4, stream);
  scatter_kernel<<<(NE + 255) / 256, 256, 0, stream>>>(ei, flag, rs, counts, ssrc);

  // ---- weight prep (fused) ----
  prep_kernel<<<(106496 + 255) / 256, 256, 0, stream>>>(W1, W2, aS1, aD1, aS2, aD2,
                                                        W1t, W2t, Wa1, Wa2);

  const int ngrid = (NN + 63) / 64;       // 782
  const int agrid = 8 * ((NN + 3) / 4);   // 100000 (head-major)
  // ---- layer 1 ----
  gemm_mfma<256, 4, false><<<ngrid, 256, 0, stream>>>(x, W1t, Wa1, hs1, alS, alD, NN);
  agg1_kernel<<<agrid, 256, 0, stream>>>(hs1, alS, alD, rs, ssrc, b1, hmid);

  // ---- layer 2 ----
  gemm_mfma<128, 2, true><<<ngrid, 256, 0, stream>>>(hmid, W2t, Wa2, hs1, alS, alD, NN);
  agg2_kernel<<<agrid, 256, 0, stream>>>(hs1, alS, alD, rs, ssrc, b2, vbuf);
  logsm_kernel<<<(NN + 3) / 4, 256, 0, stream>>>(vbuf, out);
}

// Round 11
// 240.128 us; speedup vs baseline: 1.8165x; 1.8165x over previous
//
#include <hip/hip_runtime.h>
#include <hip/hip_fp16.h>

#define NN 50000
#define NE 800000

typedef _Float16 half4v __attribute__((ext_vector_type(4)));
typedef _Float16 half8v __attribute__((ext_vector_type(8)));
typedef float f32x4 __attribute__((ext_vector_type(4)));

#define Q_SCALE 0.04724409448f   /* 6/127 */
#define Q_INV   21.16666667f     /* 127/6 */

static __device__ __forceinline__ float lrelu(float x) { return x > 0.f ? x : 0.2f * x; }

// ---------------- edge-index dtype detection (int32 vs int64) ----------------
__global__ void detect_i64_kernel(const unsigned* __restrict__ ei, int* __restrict__ flag) {
  if (threadIdx.x == 0 && blockIdx.x == 0) {
    int is64 = 1;
    for (int i = 0; i < 64; ++i)
      if (ei[2 * i + 1] != 0u) { is64 = 0; break; }
    *flag = is64;
  }
}

static __device__ __forceinline__ int edge_at(const void* ei, int is64, long long idx) {
  if (is64) return (int)((const long long*)ei)[idx];
  return ((const int*)ei)[idx];
}

// ---------------- CSR build ----------------
__global__ void count_kernel(const void* __restrict__ ei, const int* __restrict__ flag,
                             int* __restrict__ counts) {
  int e = blockIdx.x * blockDim.x + threadIdx.x;
  if (e >= NE) return;
  int is64 = *flag;
  int d = edge_at(ei, is64, (long long)NE + e);
  atomicAdd(&counts[d], 1);
}

static __device__ __forceinline__ int block_scan_inc(int v, int tid) {
  __shared__ int ws[4];
  const int lane = tid & 63, wv = tid >> 6;
  #pragma unroll
  for (int off = 1; off < 64; off <<= 1) {
    int t = __shfl_up(v, off);
    if (lane >= off) v += t;
  }
  if (lane == 63) ws[wv] = v;
  __syncthreads();
  int add = 0;
  #pragma unroll
  for (int j = 0; j < 4; ++j) if (j < wv) add += ws[j];
  return v + add;
}

__global__ void scan1_kernel(const int* __restrict__ counts, int* __restrict__ bsums) {
  __shared__ int ws[4];
  const int tid = threadIdx.x;
  const int lane = tid & 63, wv = tid >> 6;
  int i = blockIdx.x * 256 + tid;
  int v = (i < NN) ? counts[i] : 0;
  #pragma unroll
  for (int off = 1; off < 64; off <<= 1) v += __shfl_xor(v, off);
  if (lane == 0) ws[wv] = v;
  __syncthreads();
  if (tid == 0) bsums[blockIdx.x] = ws[0] + ws[1] + ws[2] + ws[3];
}

__global__ void scan2_kernel(int* __restrict__ bsums, int nb) {
  const int tid = threadIdx.x;
  int v = (tid < nb) ? bsums[tid] : 0;
  int inc = block_scan_inc(v, tid);
  if (tid < nb) bsums[tid] = inc - v;   // exclusive
}

__global__ void scan3_kernel(const int* __restrict__ counts, const int* __restrict__ bsums,
                             int* __restrict__ rs) {
  const int tid = threadIdx.x;
  int i = blockIdx.x * 256 + tid;
  int v = (i < NN) ? counts[i] : 0;
  int inc = block_scan_inc(v, tid);
  if (i < NN) rs[i + 1] = bsums[blockIdx.x] + inc;
  if (i == 0) rs[0] = 0;
}

__global__ void scatter_kernel(const void* __restrict__ ei, const int* __restrict__ flag,
                               const int* __restrict__ rs, int* __restrict__ cursor,
                               int* __restrict__ ssrc) {
  int e = blockIdx.x * blockDim.x + threadIdx.x;
  if (e >= NE) return;
  int is64 = *flag;
  int s = edge_at(ei, is64, e);
  int d = edge_at(ei, is64, (long long)NE + e);
  int p = atomicAdd(&cursor[d], 1);
  ssrc[rs[d] + p] = s;
}

// ---------------- fused weight prep: W1t, W2t, Wa1, Wa2 ----------------------
__global__ void prep_kernel(const float* __restrict__ W1, const float* __restrict__ W2,
                            const float* __restrict__ aS1, const float* __restrict__ aD1,
                            const float* __restrict__ aS2, const float* __restrict__ aD2,
                            _Float16* __restrict__ W1t, _Float16* __restrict__ W2t,
                            _Float16* __restrict__ Wa1, _Float16* __restrict__ Wa2) {
  int i = blockIdx.x * blockDim.x + threadIdx.x;
  if (i < 65536) {
    int n = i >> 8, k = i & 255;
    W1t[i] = (_Float16)W1[(size_t)k * 256 + n];
  } else if (i < 98304) {
    int j = i - 65536;
    int n = j >> 8, k = j & 255;
    W2t[j] = (_Float16)W2[(size_t)k * 128 + n];
  } else if (i < 102400) {
    int j = i - 98304;
    int row = j >> 8, k = j & 255;
    int head = row & 7;
    const float* a = (row < 8) ? aS1 : aD1;
    float s = 0.f;
    #pragma unroll 8
    for (int c = 0; c < 32; ++c)
      s += W1[(size_t)k * 256 + head * 32 + c] * a[head * 32 + c];
    Wa1[j] = (_Float16)s;
  } else if (i < 106496) {
    int j = i - 102400;
    int row = j >> 8, k = j & 255;
    int head = row & 7;
    const float* a = (row < 8) ? aS2 : aD2;
    float s = 0.f;
    #pragma unroll 8
    for (int c = 0; c < 16; ++c)
      s += W2[(size_t)k * 128 + head * 16 + c] * a[head * 16 + c];
    Wa2[j] = (_Float16)s;
  }
}

// ---------------- MFMA fp16 GEMM + fused alpha -------------------------------
// Q8OUT: C stored as offset-128 uint8 (u = round(v*127/6)+128), via LDS restage.
// else : C stored fp16 row-major.
template<int BN, int NCF, bool A_HALF, bool Q8OUT>
__global__ __launch_bounds__(256) void gemm_mfma(const void* __restrict__ Araw,
                                                 const _Float16* __restrict__ Wt,
                                                 const _Float16* __restrict__ Wa,
                                                 void* __restrict__ Cout,
                                                 float* __restrict__ alS,
                                                 float* __restrict__ alD, int M) {
  __shared__ __align__(16) _Float16 As[64][256 + 8];
  const int tid = threadIdx.x;
  const int bm0 = blockIdx.x * 64;
  if (A_HALF) {
    const _Float16* A = (const _Float16*)Araw;
    for (int idx = tid; idx < 64 * 32; idx += 256) {
      int r = idx >> 5, c8 = (idx & 31) << 3;
      int gr = bm0 + r;
      half8v v = {};
      if (gr < M) v = *(const half8v*)&A[(size_t)gr * 256 + c8];
      *(half8v*)&As[r][c8] = v;
    }
  } else {
    const float* A = (const float*)Araw;
    for (int idx = tid; idx < 64 * 64; idx += 256) {
      int r = idx >> 6, c4 = (idx & 63) << 2;
      int gr = bm0 + r;
      float4 v = make_float4(0.f, 0.f, 0.f, 0.f);
      if (gr < M) v = *(const float4*)&A[(size_t)gr * 256 + c4];
      half4v h = { (_Float16)v.x, (_Float16)v.y, (_Float16)v.z, (_Float16)v.w };
      *(half4v*)&As[r][c4] = h;
    }
  }
  __syncthreads();
  const int lane = tid & 63, wv = tid >> 6;
  const int ncol0 = wv * (16 * NCF);
  const int lrow = lane & 15, lk8 = (lane >> 4) << 3;
  f32x4 acc[4][NCF];
  f32x4 acca[4];
  #pragma unroll
  for (int rf = 0; rf < 4; ++rf) {
    acca[rf] = (f32x4){0.f, 0.f, 0.f, 0.f};
    #pragma unroll
    for (int cf = 0; cf < NCF; ++cf) acc[rf][cf] = (f32x4){0.f, 0.f, 0.f, 0.f};
  }
  #pragma unroll
  for (int k0 = 0; k0 < 256; k0 += 32) {
    const int ks = k0 + lk8;
    half8v af[4];
    #pragma unroll
    for (int rf = 0; rf < 4; ++rf)
      af[rf] = *(const half8v*)&As[16 * rf + lrow][ks];
    #pragma unroll
    for (int cf = 0; cf < NCF; ++cf) {
      half8v bf = *(const half8v*)&Wt[(size_t)(ncol0 + 16 * cf + lrow) * 256 + ks];
      #pragma unroll
      for (int rf = 0; rf < 4; ++rf)
        acc[rf][cf] = __builtin_amdgcn_mfma_f32_16x16x32_f16(af[rf], bf, acc[rf][cf], 0, 0, 0);
    }
    if (wv == 0) {
      half8v bfa = *(const half8v*)&Wa[(size_t)lrow * 256 + ks];
      #pragma unroll
      for (int rf = 0; rf < 4; ++rf)
        acca[rf] = __builtin_amdgcn_mfma_f32_16x16x32_f16(af[rf], bfa, acca[rf], 0, 0, 0);
    }
  }
  if (Q8OUT) {
    __syncthreads();                       // all waves done with As
    char* Cs = (char*)&As[0][0];           // reuse LDS: [64][256] bytes
    #pragma unroll
    for (int rf = 0; rf < 4; ++rf) {
      #pragma unroll
      for (int j = 0; j < 4; ++j) {
        int r = 16 * rf + 4 * (lane >> 4) + j;
        #pragma unroll
        for (int cf = 0; cf < NCF; ++cf) {
          int col = ncol0 + 16 * cf + lrow;
          float v = acc[rf][cf][j];
          int q = __float2int_rn(fminf(fmaxf(v * Q_INV, -127.f), 127.f)) + 128;
          Cs[r * 256 + col] = (char)q;
        }
      }
    }
    __syncthreads();
    unsigned char* C8 = (unsigned char*)Cout;
    for (int idx = tid; idx < 64 * 16; idx += 256) {
      int r = idx >> 4, c16 = idx & 15;
      int grow = bm0 + r;
      if (grow < M)
        *(int4*)&C8[(size_t)grow * 256 + 16 * c16] = *(const int4*)&Cs[r * 256 + 16 * c16];
    }
  } else {
    __half* C = (__half*)Cout;
    #pragma unroll
    for (int rf = 0; rf < 4; ++rf) {
      #pragma unroll
      for (int j = 0; j < 4; ++j) {
        int row = bm0 + 16 * rf + 4 * (lane >> 4) + j;
        if (row < M) {
          #pragma unroll
          for (int cf = 0; cf < NCF; ++cf) {
            int col = ncol0 + 16 * cf + lrow;
            C[(size_t)row * BN + col] = __float2half(acc[rf][cf][j]);
          }
        }
      }
    }
  }
  if (wv == 0) {
    #pragma unroll
    for (int rf = 0; rf < 4; ++rf) {
      #pragma unroll
      for (int j = 0; j < 4; ++j) {
        int row = bm0 + 16 * rf + 4 * (lane >> 4) + j;
        if (row < M) {
          float v = acca[rf][j];
          if (lrow < 8) alS[row * 8 + lrow] = v;
          else          alD[row * 8 + (lrow - 8)] = v;
        }
      }
    }
  }
}

// ---------------- layer-1 aggregation: int8 gather-FMA ----------------------
// one wave per node; h1 as offset-128 uint8 (4 ch/lane = one dword);
// acc = S*(accU - 128*denom) applied once at the end.
#define ACCQ(w, p) do { \
    ax0 += (p) * (float)((w) & 255u); \
    ax1 += (p) * (float)(((w) >> 8) & 255u); \
    ax2 += (p) * (float)(((w) >> 16) & 255u); \
    ax3 += (p) * (float)((w) >> 24); \
  } while (0)

__global__ __launch_bounds__(256) void agg1_kernel(const unsigned char* __restrict__ h1q,
    const float* __restrict__ as, const float* __restrict__ ad,
    const int* __restrict__ rs, const int* __restrict__ ssrc,
    const float* __restrict__ bias, __half* __restrict__ out) {
  const int wid = (blockIdx.x * blockDim.x + threadIdx.x) >> 6;
  const int lane = threadIdx.x & 63;
  if (wid >= NN) return;
  const int node = wid;
  const int beg = rs[node], end = rs[node + 1];
  const int deg = end - beg;
  const int hd = lane >> 3;
  const float advh = ad[node * 8 + hd];
  const unsigned* hw = (const unsigned*)h1q;   // [NN][64] dwords
  float denom = 0.f;
  float ax0 = 0.f, ax1 = 0.f, ax2 = 0.f, ax3 = 0.f;
  {
    float p = __expf(lrelu(as[node * 8 + hd] + advh));   // self loop
    unsigned w = hw[(size_t)node * 64 + lane];
    ACCQ(w, p);
    denom = p;
  }
  for (int base = 0; base < deg; base += 64) {
    const int cnt = min(deg - base, 64);
    int sv = (lane < cnt) ? ssrc[beg + base + lane] : 0;  // one coalesced load
    int j = 0;
    for (; j + 8 <= cnt; j += 8) {
      int s0 = __builtin_amdgcn_readlane(sv, j + 0);
      int s1 = __builtin_amdgcn_readlane(sv, j + 1);
      int s2 = __builtin_amdgcn_readlane(sv, j + 2);
      int s3 = __builtin_amdgcn_readlane(sv, j + 3);
      int s4 = __builtin_amdgcn_readlane(sv, j + 4);
      int s5 = __builtin_amdgcn_readlane(sv, j + 5);
      int s6 = __builtin_amdgcn_readlane(sv, j + 6);
      int s7 = __builtin_amdgcn_readlane(sv, j + 7);
      float b0 = as[s0 * 8 + hd], b1 = as[s1 * 8 + hd];
      float b2 = as[s2 * 8 + hd], b3 = as[s3 * 8 + hd];
      float b4 = as[s4 * 8 + hd], b5 = as[s5 * 8 + hd];
      float b6 = as[s6 * 8 + hd], b7 = as[s7 * 8 + hd];
      unsigned w0 = hw[(size_t)s0 * 64 + lane];
      unsigned w1 = hw[(size_t)s1 * 64 + lane];
      unsigned w2 = hw[(size_t)s2 * 64 + lane];
      unsigned w3 = hw[(size_t)s3 * 64 + lane];
      unsigned w4 = hw[(size_t)s4 * 64 + lane];
      unsigned w5 = hw[(size_t)s5 * 64 + lane];
      unsigned w6 = hw[(size_t)s6 * 64 + lane];
      unsigned w7 = hw[(size_t)s7 * 64 + lane];
      float p0 = __expf(lrelu(b0 + advh)), p1 = __expf(lrelu(b1 + advh));
      float p2 = __expf(lrelu(b2 + advh)), p3 = __expf(lrelu(b3 + advh));
      float p4 = __expf(lrelu(b4 + advh)), p5 = __expf(lrelu(b5 + advh));
      float p6 = __expf(lrelu(b6 + advh)), p7 = __expf(lrelu(b7 + advh));
      denom += (p0 + p1) + (p2 + p3) + ((p4 + p5) + (p6 + p7));
      ACCQ(w0, p0); ACCQ(w1, p1); ACCQ(w2, p2); ACCQ(w3, p3);
      ACCQ(w4, p4); ACCQ(w5, p5); ACCQ(w6, p6); ACCQ(w7, p7);
    }
    for (; j < cnt; ++j) {
      int s = __builtin_amdgcn_readlane(sv, j);
      float p = __expf(lrelu(as[s * 8 + hd] + advh));
      unsigned w = hw[(size_t)s * 64 + lane];
      ACCQ(w, p);
      denom += p;
    }
  }
  const float inv = 1.f / (denom + 1e-16f);
  const float4 bv = *(const float4*)&bias[lane * 4];
  float4 o;
  o.x = Q_SCALE * (ax0 * inv - 128.f) + bv.x;
  o.y = Q_SCALE * (ax1 * inv - 128.f) + bv.y;
  o.z = Q_SCALE * (ax2 * inv - 128.f) + bv.z;
  o.w = Q_SCALE * (ax3 * inv - 128.f) + bv.w;
  o.x = o.x > 0.f ? o.x : __expf(o.x) - 1.f;
  o.y = o.y > 0.f ? o.y : __expf(o.y) - 1.f;
  o.z = o.z > 0.f ? o.z : __expf(o.z) - 1.f;
  o.w = o.w > 0.f ? o.w : __expf(o.w) - 1.f;
  union { __half2 h2[2]; float2 f2; } w;
  w.h2[0] = __floats2half2_rn(o.x, o.y);
  w.h2[1] = __floats2half2_rn(o.z, o.w);
  *(float2*)&out[(size_t)node * 256 + lane * 4] = w.f2;
}

// ---------------- layer-2 aggregation + bias + log_softmax ------------------
__global__ __launch_bounds__(256) void agg2_kernel(const __half* __restrict__ h,
    const float* __restrict__ as, const float* __restrict__ ad,
    const int* __restrict__ rs, const int* __restrict__ ssrc,
    const float* __restrict__ bias, float* __restrict__ out) {
  const int wid = (blockIdx.x * blockDim.x + threadIdx.x) >> 6;
  const int lane = threadIdx.x & 63;
  if (wid >= NN) return;
  const int node = wid;
  const int beg = rs[node], end = rs[node + 1];
  const int deg = end - beg;
  const int hd = lane >> 3;
  const float advh = ad[node * 8 + hd];
  float denom;
  __half2 acc;
  {
    float p = __expf(lrelu(as[node * 8 + hd] + advh));   // self loop
    __half2 q = ((const __half2*)&h[(size_t)node * 128])[lane];
    acc = __hmul2(__float2half2_rn(p), q);
    denom = p;
  }
  for (int base = 0; base < deg; base += 64) {
    const int cnt = min(deg - base, 64);
    int sv = (lane < cnt) ? ssrc[beg + base + lane] : 0;
    int j = 0;
    for (; j + 8 <= cnt; j += 8) {
      int s0 = __builtin_amdgcn_readlane(sv, j + 0);
      int s1 = __builtin_amdgcn_readlane(sv, j + 1);
      int s2 = __builtin_amdgcn_readlane(sv, j + 2);
      int s3 = __builtin_amdgcn_readlane(sv, j + 3);
      int s4 = __builtin_amdgcn_readlane(sv, j + 4);
      int s5 = __builtin_amdgcn_readlane(sv, j + 5);
      int s6 = __builtin_amdgcn_readlane(sv, j + 6);
      int s7 = __builtin_amdgcn_readlane(sv, j + 7);
      float b0 = as[s0 * 8 + hd], b1 = as[s1 * 8 + hd];
      float b2 = as[s2 * 8 + hd], b3 = as[s3 * 8 + hd];
      float b4 = as[s4 * 8 + hd], b5 = as[s5 * 8 + hd];
      float b6 = as[s6 * 8 + hd], b7 = as[s7 * 8 + hd];
      __half2 q0 = ((const __half2*)&h[(size_t)s0 * 128])[lane];
      __half2 q1 = ((const __half2*)&h[(size_t)s1 * 128])[lane];
      __half2 q2 = ((const __half2*)&h[(size_t)s2 * 128])[lane];
      __half2 q3 = ((const __half2*)&h[(size_t)s3 * 128])[lane];
      __half2 q4 = ((const __half2*)&h[(size_t)s4 * 128])[lane];
      __half2 q5 = ((const __half2*)&h[(size_t)s5 * 128])[lane];
      __half2 q6 = ((const __half2*)&h[(size_t)s6 * 128])[lane];
      __half2 q7 = ((const __half2*)&h[(size_t)s7 * 128])[lane];
      float p0 = __expf(lrelu(b0 + advh)), p1 = __expf(lrelu(b1 + advh));
      float p2 = __expf(lrelu(b2 + advh)), p3 = __expf(lrelu(b3 + advh));
      float p4 = __expf(lrelu(b4 + advh)), p5 = __expf(lrelu(b5 + advh));
      float p6 = __expf(lrelu(b6 + advh)), p7 = __expf(lrelu(b7 + advh));
      denom += (p0 + p1) + (p2 + p3) + ((p4 + p5) + (p6 + p7));
      acc = __hfma2(__float2half2_rn(p0), q0, acc);
      acc = __hfma2(__float2half2_rn(p1), q1, acc);
      acc = __hfma2(__float2half2_rn(p2), q2, acc);
      acc = __hfma2(__float2half2_rn(p3), q3, acc);
      acc = __hfma2(__float2half2_rn(p4), q4, acc);
      acc = __hfma2(__float2half2_rn(p5), q5, acc);
      acc = __hfma2(__float2half2_rn(p6), q6, acc);
      acc = __hfma2(__float2half2_rn(p7), q7, acc);
    }
    for (; j < cnt; ++j) {
      int s = __builtin_amdgcn_readlane(sv, j);
      float p = __expf(lrelu(as[s * 8 + hd] + advh));
      __half2 q = ((const __half2*)&h[(size_t)s * 128])[lane];
      acc = __hfma2(__float2half2_rn(p), q, acc);
      denom += p;
    }
  }
  const float inv = 1.f / (denom + 1e-16f);
  float2 av = __half22float2(acc);
  float v0 = av.x * inv + bias[lane * 2 + 0];
  float v1 = av.y * inv + bias[lane * 2 + 1];
  float mx = fmaxf(v0, v1);
  #pragma unroll
  for (int off = 1; off < 64; off <<= 1) mx = fmaxf(mx, __shfl_xor(mx, off));
  float sum = __expf(v0 - mx) + __expf(v1 - mx);
  #pragma unroll
  for (int off = 1; off < 64; off <<= 1) sum += __shfl_xor(sum, off);
  float lse = mx + __logf(sum);
  float2 o = make_float2(v0 - lse, v1 - lse);
  __builtin_nontemporal_store(o.x, &out[(size_t)node * 128 + lane * 2]);
  __builtin_nontemporal_store(o.y, &out[(size_t)node * 128 + lane * 2 + 1]);
}

// ---------------- host ----------------
extern "C" void kernel_launch(void* const* d_in, const int* in_sizes, int n_in,
                              void* d_out, int out_size, void* d_ws, size_t ws_size,
                              hipStream_t stream) {
  const float* x    = (const float*)d_in[0];
  const void*  ei   = d_in[1];
  const float* W1   = (const float*)d_in[2];
  const float* aS1  = (const float*)d_in[3];
  const float* aD1  = (const float*)d_in[4];
  const float* b1   = (const float*)d_in[5];
  const float* W2   = (const float*)d_in[6];
  const float* aS2  = (const float*)d_in[7];
  const float* aD2  = (const float*)d_in[8];
  const float* b2   = (const float*)d_in[9];
  float* out = (float*)d_out;

  char* ws = (char*)d_ws;
  unsigned char* h1q = (unsigned char*)ws; ws += (size_t)NN * 256;   // int8 h1 (offset-128)
  __half* h2   = (__half*)ws;          ws += (size_t)NN * 128 * 2;   // fp16 h2
  __half* hmid = (__half*)ws;          ws += (size_t)NN * 256 * 2;   // ELU(agg1) fp16
  _Float16* W1t = (_Float16*)ws;       ws += (size_t)256 * 256 * 2;
  _Float16* W2t = (_Float16*)ws;       ws += (size_t)128 * 256 * 2;
  _Float16* Wa1 = (_Float16*)ws;       ws += (size_t)16 * 256 * 2;
  _Float16* Wa2 = (_Float16*)ws;       ws += (size_t)16 * 256 * 2;
  float* alS  = (float*)ws;            ws += (size_t)NN * 8 * 4;
  float* alD  = (float*)ws;            ws += (size_t)NN * 8 * 4;
  int* counts = (int*)ws;              ws += (size_t)NN * 4;
  int* rs     = (int*)ws;              ws += (size_t)(NN + 1) * 4;
  int* bsums  = (int*)ws;              ws += (size_t)256 * 4;
  int* ssrc   = (int*)ws;              ws += (size_t)NE * 4;
  int* flag   = (int*)ws;              ws += 256;

  const int NB = (NN + 255) / 256;

  // ---- CSR build ----
  detect_i64_kernel<<<1, 64, 0, stream>>>((const unsigned*)ei, flag);
  hipMemsetAsync(counts, 0, (size_t)NN * 4, stream);
  count_kernel<<<(NE + 255) / 256, 256, 0, stream>>>(ei, flag, counts);
  scan1_kernel<<<NB, 256, 0, stream>>>(counts, bsums);
  scan2_kernel<<<1, 256, 0, stream>>>(bsums, NB);
  scan3_kernel<<<NB, 256, 0, stream>>>(counts, bsums, rs);
  hipMemsetAsync(counts, 0, (size_t)NN * 4, stream);
  scatter_kernel<<<(NE + 255) / 256, 256, 0, stream>>>(ei, flag, rs, counts, ssrc);

  // ---- weight prep (fused) ----
  prep_kernel<<<(106496 + 255) / 256, 256, 0, stream>>>(W1, W2, aS1, aD1, aS2, aD2,
                                                        W1t, W2t, Wa1, Wa2);

  const int ngrid = (NN + 63) / 64;  // 782
  // ---- layer 1 ----
  gemm_mfma<256, 4, false, true><<<ngrid, 256, 0, stream>>>(x, W1t, Wa1, h1q, alS, alD, NN);
  agg1_kernel<<<(NN + 3) / 4, 256, 0, stream>>>(h1q, alS, alD, rs, ssrc, b1, hmid);

  // ---- layer 2 ----
  gemm_mfma<128, 2, true, false><<<ngrid, 256, 0, stream>>>(hmid, W2t, Wa2, h2, alS, alD, NN);
  agg2_kernel<<<(NN + 3) / 4, 256, 0, stream>>>(h2, alS, alD, rs, ssrc, b2, out);
}

// Round 12
// 220.796 us; speedup vs baseline: 1.9755x; 1.0876x over previous
//
#include <hip/hip_runtime.h>
#include <hip/hip_fp16.h>

#define NN 50000
#define NE 800000

typedef _Float16 half4v __attribute__((ext_vector_type(4)));
typedef _Float16 half8v __attribute__((ext_vector_type(8)));
typedef float f32x4 __attribute__((ext_vector_type(4)));

#define Q_SCALE 0.04724409448f   /* 6/127 */
#define Q_INV   21.16666667f     /* 127/6 */

static __device__ __forceinline__ float lrelu(float x) { return x > 0.f ? x : 0.2f * x; }

// ---------------- edge-index dtype detection (int32 vs int64) ----------------
__global__ void detect_i64_kernel(const unsigned* __restrict__ ei, int* __restrict__ flag) {
  if (threadIdx.x == 0 && blockIdx.x == 0) {
    int is64 = 1;
    for (int i = 0; i < 64; ++i)
      if (ei[2 * i + 1] != 0u) { is64 = 0; break; }
    *flag = is64;
  }
}

static __device__ __forceinline__ int edge_at(const void* ei, int is64, long long idx) {
  if (is64) return (int)((const long long*)ei)[idx];
  return ((const int*)ei)[idx];
}

// ---------------- CSR build ----------------
__global__ void count_kernel(const void* __restrict__ ei, const int* __restrict__ flag,
                             int* __restrict__ counts) {
  int e = blockIdx.x * blockDim.x + threadIdx.x;
  if (e >= NE) return;
  int is64 = *flag;
  int d = edge_at(ei, is64, (long long)NE + e);
  atomicAdd(&counts[d], 1);
}

static __device__ __forceinline__ int block_scan_inc(int v, int tid) {
  __shared__ int ws[4];
  const int lane = tid & 63, wv = tid >> 6;
  #pragma unroll
  for (int off = 1; off < 64; off <<= 1) {
    int t = __shfl_up(v, off);
    if (lane >= off) v += t;
  }
  if (lane == 63) ws[wv] = v;
  __syncthreads();
  int add = 0;
  #pragma unroll
  for (int j = 0; j < 4; ++j) if (j < wv) add += ws[j];
  return v + add;
}

__global__ void scan1_kernel(const int* __restrict__ counts, int* __restrict__ bsums) {
  __shared__ int ws[4];
  const int tid = threadIdx.x;
  const int lane = tid & 63, wv = tid >> 6;
  int i = blockIdx.x * 256 + tid;
  int v = (i < NN) ? counts[i] : 0;
  #pragma unroll
  for (int off = 1; off < 64; off <<= 1) v += __shfl_xor(v, off);
  if (lane == 0) ws[wv] = v;
  __syncthreads();
  if (tid == 0) bsums[blockIdx.x] = ws[0] + ws[1] + ws[2] + ws[3];
}

__global__ void scan2_kernel(int* __restrict__ bsums, int nb) {
  const int tid = threadIdx.x;
  int v = (tid < nb) ? bsums[tid] : 0;
  int inc = block_scan_inc(v, tid);
  if (tid < nb) bsums[tid] = inc - v;   // exclusive
}

__global__ void scan3_kernel(const int* __restrict__ counts, const int* __restrict__ bsums,
                             int* __restrict__ rs) {
  const int tid = threadIdx.x;
  int i = blockIdx.x * 256 + tid;
  int v = (i < NN) ? counts[i] : 0;
  int inc = block_scan_inc(v, tid);
  if (i < NN) rs[i + 1] = bsums[blockIdx.x] + inc;
  if (i == 0) rs[0] = 0;
}

__global__ void scatter_kernel(const void* __restrict__ ei, const int* __restrict__ flag,
                               const int* __restrict__ rs, int* __restrict__ cursor,
                               int* __restrict__ ssrc) {
  int e = blockIdx.x * blockDim.x + threadIdx.x;
  if (e >= NE) return;
  int is64 = *flag;
  int s = edge_at(ei, is64, e);
  int d = edge_at(ei, is64, (long long)NE + e);
  int p = atomicAdd(&cursor[d], 1);
  ssrc[rs[d] + p] = s;
}

// ---------------- fused weight prep: packed MFMA B-fragments -----------------
// Bp layout: [(ct*8 + kst)*64 + lane]*8 + j  where col = ct*16 + (lane&15),
// k = kst*32 + 8*(lane>>4) + j.  Wap: [kst*64+lane]*8+j, col = lane&15.
// ranges: [0,65536) W1p ; [65536,98304) W2p ; [98304,102400) Wa1p ; [102400,106496) Wa2p
__global__ void prep_kernel(const float* __restrict__ W1, const float* __restrict__ W2,
                            const float* __restrict__ aS1, const float* __restrict__ aD1,
                            const float* __restrict__ aS2, const float* __restrict__ aD2,
                            _Float16* __restrict__ W1p, _Float16* __restrict__ W2p,
                            _Float16* __restrict__ Wa1p, _Float16* __restrict__ Wa2p) {
  int i = blockIdx.x * blockDim.x + threadIdx.x;
  if (i < 65536) {
    int j = i & 7, l = (i >> 3) & 63, kst = (i >> 9) & 7, ct = i >> 12;
    int col = ct * 16 + (l & 15);
    int k = kst * 32 + ((l >> 4) << 3) + j;
    W1p[i] = (_Float16)W1[(size_t)k * 256 + col];
  } else if (i < 98304) {
    int n = i - 65536;
    int j = n & 7, l = (n >> 3) & 63, kst = (n >> 9) & 7, ct = n >> 12;
    int col = ct * 16 + (l & 15);
    int k = kst * 32 + ((l >> 4) << 3) + j;
    W2p[n] = (_Float16)W2[(size_t)k * 128 + col];
  } else if (i < 102400) {
    int n = i - 98304;
    int j = n & 7, l = (n >> 3) & 63, kst = n >> 9;
    int row = l & 15;
    int head = row & 7;
    const float* a = (row < 8) ? aS1 : aD1;
    int k = kst * 32 + ((l >> 4) << 3) + j;
    float s = 0.f;
    #pragma unroll 8
    for (int c = 0; c < 32; ++c)
      s += W1[(size_t)k * 256 + head * 32 + c] * a[head * 32 + c];
    Wa1p[n] = (_Float16)s;
  } else if (i < 106496) {
    int n = i - 102400;
    int j = n & 7, l = (n >> 3) & 63, kst = n >> 9;
    int row = l & 15;
    int head = row & 7;
    const float* a = (row < 8) ? aS2 : aD2;
    int k = kst * 32 + ((l >> 4) << 3) + j;
    float s = 0.f;
    #pragma unroll 8
    for (int c = 0; c < 16; ++c)
      s += W2[(size_t)k * 128 + head * 16 + c] * a[head * 16 + c];
    Wa2p[n] = (_Float16)s;
  }
}

// ---------------- MFMA fp16 GEMM, 8 waves, packed-B, fused alpha -------------
// BN cols total; 8 waves x NCF col-tiles of 16 (BN = 128*NCF).
// Q8OUT: C as offset-128 uint8 via padded-LDS restage; else fp16 row-major.
template<int BN, int NCF, bool A_HALF, bool Q8OUT>
__global__ __launch_bounds__(512) void gemm_mfma(const void* __restrict__ Araw,
                                                 const _Float16* __restrict__ Bp,
                                                 const _Float16* __restrict__ Wap,
                                                 void* __restrict__ Cout,
                                                 float* __restrict__ alS,
                                                 float* __restrict__ alD, int M) {
  __shared__ __align__(16) _Float16 As[64][256 + 8];
  const int tid = threadIdx.x;
  const int bm0 = blockIdx.x * 64;
  // ---- batched A staging (loads in flight before converts) ----
  if (A_HALF) {
    const _Float16* A = (const _Float16*)Araw;
    half8v tmp[4]; int rr[4], cc[4];
    #pragma unroll
    for (int t = 0; t < 4; ++t) {
      int idx = tid + t * 512;
      int r = idx >> 5, c8 = (idx & 31) << 3;
      int gr = bm0 + r;
      tmp[t] = (half8v){};
      if (gr < M) tmp[t] = *(const half8v*)&A[(size_t)gr * 256 + c8];
      rr[t] = r; cc[t] = c8;
    }
    #pragma unroll
    for (int t = 0; t < 4; ++t)
      *(half8v*)&As[rr[t]][cc[t]] = tmp[t];
  } else {
    const float* A = (const float*)Araw;
    #pragma unroll
    for (int g = 0; g < 2; ++g) {
      float4 tmp[4]; int rr[4], cc[4];
      #pragma unroll
      for (int t = 0; t < 4; ++t) {
        int idx = tid + (g * 4 + t) * 512;
        int r = idx >> 6, c4 = (idx & 63) << 2;
        int gr = bm0 + r;
        tmp[t] = make_float4(0.f, 0.f, 0.f, 0.f);
        if (gr < M) tmp[t] = *(const float4*)&A[(size_t)gr * 256 + c4];
        rr[t] = r; cc[t] = c4;
      }
      #pragma unroll
      for (int t = 0; t < 4; ++t) {
        half4v h = { (_Float16)tmp[t].x, (_Float16)tmp[t].y,
                     (_Float16)tmp[t].z, (_Float16)tmp[t].w };
        *(half4v*)&As[rr[t]][cc[t]] = h;
      }
    }
  }
  __syncthreads();
  const int lane = tid & 63, wv = tid >> 6;        // 8 waves
  const int ncol0 = wv * (16 * NCF);
  const int lrow = lane & 15, lk8 = (lane >> 4) << 3;
  f32x4 acc[4][NCF];
  f32x4 acca[4];
  #pragma unroll
  for (int rf = 0; rf < 4; ++rf) {
    acca[rf] = (f32x4){0.f, 0.f, 0.f, 0.f};
    #pragma unroll
    for (int cf = 0; cf < NCF; ++cf) acc[rf][cf] = (f32x4){0.f, 0.f, 0.f, 0.f};
  }
  #pragma unroll
  for (int kst = 0; kst < 8; ++kst) {
    const int ks = kst * 32 + lk8;
    half8v af[4];
    #pragma unroll
    for (int rf = 0; rf < 4; ++rf)
      af[rf] = *(const half8v*)&As[16 * rf + lrow][ks];
    #pragma unroll
    for (int cf = 0; cf < NCF; ++cf) {
      // coalesced packed fragment: 16B per lane, lane-contiguous
      half8v bf = *(const half8v*)&Bp[((size_t)((wv * NCF + cf) * 8 + kst) * 64 + lane) * 8];
      #pragma unroll
      for (int rf = 0; rf < 4; ++rf)
        acc[rf][cf] = __builtin_amdgcn_mfma_f32_16x16x32_f16(af[rf], bf, acc[rf][cf], 0, 0, 0);
    }
    if (wv == 0) {
      half8v bfa = *(const half8v*)&Wap[((size_t)kst * 64 + lane) * 8];
      #pragma unroll
      for (int rf = 0; rf < 4; ++rf)
        acca[rf] = __builtin_amdgcn_mfma_f32_16x16x32_f16(af[rf], bfa, acca[rf], 0, 0, 0);
    }
  }
  if (Q8OUT) {
    __syncthreads();                       // all waves done reading As
    char* Cs = (char*)&As[0][0];           // reuse LDS: [64] rows x 272B (padded)
    #pragma unroll
    for (int rf = 0; rf < 4; ++rf) {
      #pragma unroll
      for (int j = 0; j < 4; ++j) {
        int r = 16 * rf + 4 * ((lane >> 4) & 3) + j;
        #pragma unroll
        for (int cf = 0; cf < NCF; ++cf) {
          int col = ncol0 + 16 * cf + lrow;
          float v = acc[rf][cf][j];
          int q = __float2int_rn(fminf(fmaxf(v * Q_INV, -127.f), 127.f)) + 128;
          Cs[r * 272 + col] = (char)q;
        }
      }
    }
    __syncthreads();
    unsigned char* C8 = (unsigned char*)Cout;
    #pragma unroll
    for (int g = 0; g < 2; ++g) {
      int idx = tid + g * 512;
      int r = idx >> 4, c16 = idx & 15;
      int grow = bm0 + r;
      if (grow < M)
        *(int4*)&C8[(size_t)grow * 256 + 16 * c16] = *(const int4*)&Cs[r * 272 + 16 * c16];
    }
  } else {
    __half* C = (__half*)Cout;
    #pragma unroll
    for (int rf = 0; rf < 4; ++rf) {
      #pragma unroll
      for (int j = 0; j < 4; ++j) {
        int row = bm0 + 16 * rf + 4 * ((lane >> 4) & 3) + j;
        if (row < M) {
          #pragma unroll
          for (int cf = 0; cf < NCF; ++cf) {
            int col = ncol0 + 16 * cf + lrow;
            C[(size_t)row * BN + col] = __float2half(acc[rf][cf][j]);
          }
        }
      }
    }
  }
  if (wv == 0) {
    #pragma unroll
    for (int rf = 0; rf < 4; ++rf) {
      #pragma unroll
      for (int j = 0; j < 4; ++j) {
        int row = bm0 + 16 * rf + 4 * ((lane >> 4) & 3) + j;
        if (row < M) {
          float v = acca[rf][j];
          if (lrow < 8) alS[row * 8 + lrow] = v;
          else          alD[row * 8 + (lrow - 8)] = v;
        }
      }
    }
  }
}

// ---------------- layer-1 aggregation: int8 gather-FMA ----------------------
#define ACCQ(w, p) do { \
    ax0 += (p) * (float)((w) & 255u); \
    ax1 += (p) * (float)(((w) >> 8) & 255u); \
    ax2 += (p) * (float)(((w) >> 16) & 255u); \
    ax3 += (p) * (float)((w) >> 24); \
  } while (0)

__global__ __launch_bounds__(256) void agg1_kernel(const unsigned char* __restrict__ h1q,
    const float* __restrict__ as, const float* __restrict__ ad,
    const int* __restrict__ rs, const int* __restrict__ ssrc,
    const float* __restrict__ bias, __half* __restrict__ out) {
  const int wid = (blockIdx.x * blockDim.x + threadIdx.x) >> 6;
  const int lane = threadIdx.x & 63;
  if (wid >= NN) return;
  const int node = wid;
  const int beg = rs[node], end = rs[node + 1];
  const int deg = end - beg;
  const int hd = lane >> 3;
  const float advh = ad[node * 8 + hd];
  const unsigned* hw = (const unsigned*)h1q;   // [NN][64] dwords
  float denom = 0.f;
  float ax0 = 0.f, ax1 = 0.f, ax2 = 0.f, ax3 = 0.f;
  {
    float p = __expf(lrelu(as[node * 8 + hd] + advh));   // self loop
    unsigned w = hw[(size_t)node * 64 + lane];
    ACCQ(w, p);
    denom = p;
  }
  for (int base = 0; base < deg; base += 64) {
    const int cnt = min(deg - base, 64);
    int sv = (lane < cnt) ? ssrc[beg + base + lane] : 0;  // one coalesced load
    int j = 0;
    for (; j + 8 <= cnt; j += 8) {
      int s0 = __builtin_amdgcn_readlane(sv, j + 0);
      int s1 = __builtin_amdgcn_readlane(sv, j + 1);
      int s2 = __builtin_amdgcn_readlane(sv, j + 2);
      int s3 = __builtin_amdgcn_readlane(sv, j + 3);
      int s4 = __builtin_amdgcn_readlane(sv, j + 4);
      int s5 = __builtin_amdgcn_readlane(sv, j + 5);
      int s6 = __builtin_amdgcn_readlane(sv, j + 6);
      int s7 = __builtin_amdgcn_readlane(sv, j + 7);
      float b0 = as[s0 * 8 + hd], b1 = as[s1 * 8 + hd];
      float b2 = as[s2 * 8 + hd], b3 = as[s3 * 8 + hd];
      float b4 = as[s4 * 8 + hd], b5 = as[s5 * 8 + hd];
      float b6 = as[s6 * 8 + hd], b7 = as[s7 * 8 + hd];
      unsigned w0 = hw[(size_t)s0 * 64 + lane];
      unsigned w1 = hw[(size_t)s1 * 64 + lane];
      unsigned w2 = hw[(size_t)s2 * 64 + lane];
      unsigned w3 = hw[(size_t)s3 * 64 + lane];
      unsigned w4 = hw[(size_t)s4 * 64 + lane];
      unsigned w5 = hw[(size_t)s5 * 64 + lane];
      unsigned w6 = hw[(size_t)s6 * 64 + lane];
      unsigned w7 = hw[(size_t)s7 * 64 + lane];
      float p0 = __expf(lrelu(b0 + advh)), p1 = __expf(lrelu(b1 + advh));
      float p2 = __expf(lrelu(b2 + advh)), p3 = __expf(lrelu(b3 + advh));
      float p4 = __expf(lrelu(b4 + advh)), p5 = __expf(lrelu(b5 + advh));
      float p6 = __expf(lrelu(b6 + advh)), p7 = __expf(lrelu(b7 + advh));
      denom += (p0 + p1) + (p2 + p3) + ((p4 + p5) + (p6 + p7));
      ACCQ(w0, p0); ACCQ(w1, p1); ACCQ(w2, p2); ACCQ(w3, p3);
      ACCQ(w4, p4); ACCQ(w5, p5); ACCQ(w6, p6); ACCQ(w7, p7);
    }
    for (; j < cnt; ++j) {
      int s = __builtin_amdgcn_readlane(sv, j);
      float p = __expf(lrelu(as[s * 8 + hd] + advh));
      unsigned w = hw[(size_t)s * 64 + lane];
      ACCQ(w, p);
      denom += p;
    }
  }
  const float inv = 1.f / (denom + 1e-16f);
  const float4 bv = *(const float4*)&bias[lane * 4];
  float4 o;
  o.x = Q_SCALE * (ax0 * inv - 128.f) + bv.x;
  o.y = Q_SCALE * (ax1 * inv - 128.f) + bv.y;
  o.z = Q_SCALE * (ax2 * inv - 128.f) + bv.z;
  o.w = Q_SCALE * (ax3 * inv - 128.f) + bv.w;
  o.x = o.x > 0.f ? o.x : __expf(o.x) - 1.f;
  o.y = o.y > 0.f ? o.y : __expf(o.y) - 1.f;
  o.z = o.z > 0.f ? o.z : __expf(o.z) - 1.f;
  o.w = o.w > 0.f ? o.w : __expf(o.w) - 1.f;
  union { __half2 h2[2]; float2 f2; } w;
  w.h2[0] = __floats2half2_rn(o.x, o.y);
  w.h2[1] = __floats2half2_rn(o.z, o.w);
  *(float2*)&out[(size_t)node * 256 + lane * 4] = w.f2;
}

// ---------------- layer-2 aggregation + bias + log_softmax ------------------
__global__ __launch_bounds__(256) void agg2_kernel(const __half* __restrict__ h,
    const float* __restrict__ as, const float* __restrict__ ad,
    const int* __restrict__ rs, const int* __restrict__ ssrc,
    const float* __restrict__ bias, float* __restrict__ out) {
  const int wid = (blockIdx.x * blockDim.x + threadIdx.x) >> 6;
  const int lane = threadIdx.x & 63;
  if (wid >= NN) return;
  const int node = wid;
  const int beg = rs[node], end = rs[node + 1];
  const int deg = end - beg;
  const int hd = lane >> 3;
  const float advh = ad[node * 8 + hd];
  float denom;
  __half2 acc;
  {
    float p = __expf(lrelu(as[node * 8 + hd] + advh));   // self loop
    __half2 q = ((const __half2*)&h[(size_t)node * 128])[lane];
    acc = __hmul2(__float2half2_rn(p), q);
    denom = p;
  }
  for (int base = 0; base < deg; base += 64) {
    const int cnt = min(deg - base, 64);
    int sv = (lane < cnt) ? ssrc[beg + base + lane] : 0;
    int j = 0;
    for (; j + 8 <= cnt; j += 8) {
      int s0 = __builtin_amdgcn_readlane(sv, j + 0);
      int s1 = __builtin_amdgcn_readlane(sv, j + 1);
      int s2 = __builtin_amdgcn_readlane(sv, j + 2);
      int s3 = __builtin_amdgcn_readlane(sv, j + 3);
      int s4 = __builtin_amdgcn_readlane(sv, j + 4);
      int s5 = __builtin_amdgcn_readlane(sv, j + 5);
      int s6 = __builtin_amdgcn_readlane(sv, j + 6);
      int s7 = __builtin_amdgcn_readlane(sv, j + 7);
      float b0 = as[s0 * 8 + hd], b1 = as[s1 * 8 + hd];
      float b2 = as[s2 * 8 + hd], b3 = as[s3 * 8 + hd];
      float b4 = as[s4 * 8 + hd], b5 = as[s5 * 8 + hd];
      float b6 = as[s6 * 8 + hd], b7 = as[s7 * 8 + hd];
      __half2 q0 = ((const __half2*)&h[(size_t)s0 * 128])[lane];
      __half2 q1 = ((const __half2*)&h[(size_t)s1 * 128])[lane];
      __half2 q2 = ((const __half2*)&h[(size_t)s2 * 128])[lane];
      __half2 q3 = ((const __half2*)&h[(size_t)s3 * 128])[lane];
      __half2 q4 = ((const __half2*)&h[(size_t)s4 * 128])[lane];
      __half2 q5 = ((const __half2*)&h[(size_t)s5 * 128])[lane];
      __half2 q6 = ((const __half2*)&h[(size_t)s6 * 128])[lane];
      __half2 q7 = ((const __half2*)&h[(size_t)s7 * 128])[lane];
      float p0 = __expf(lrelu(b0 + advh)), p1 = __expf(lrelu(b1 + advh));
      float p2 = __expf(lrelu(b2 + advh)), p3 = __expf(lrelu(b3 + advh));
      float p4 = __expf(lrelu(b4 + advh)), p5 = __expf(lrelu(b5 + advh));
      float p6 = __expf(lrelu(b6 + advh)), p7 = __expf(lrelu(b7 + advh));
      denom += (p0 + p1) + (p2 + p3) + ((p4 + p5) + (p6 + p7));
      acc = __hfma2(__float2half2_rn(p0), q0, acc);
      acc = __hfma2(__float2half2_rn(p1), q1, acc);
      acc = __hfma2(__float2half2_rn(p2), q2, acc);
      acc = __hfma2(__float2half2_rn(p3), q3, acc);
      acc = __hfma2(__float2half2_rn(p4), q4, acc);
      acc = __hfma2(__float2half2_rn(p5), q5, acc);
      acc = __hfma2(__float2half2_rn(p6), q6, acc);
      acc = __hfma2(__float2half2_rn(p7), q7, acc);
    }
    for (; j < cnt; ++j) {
      int s = __builtin_amdgcn_readlane(sv, j);
      float p = __expf(lrelu(as[s * 8 + hd] + advh));
      __half2 q = ((const __half2*)&h[(size_t)s * 128])[lane];
      acc = __hfma2(__float2half2_rn(p), q, acc);
      denom += p;
    }
  }
  const float inv = 1.f / (denom + 1e-16f);
  float2 av = __half22float2(acc);
  float v0 = av.x * inv + bias[lane * 2 + 0];
  float v1 = av.y * inv + bias[lane * 2 + 1];
  float mx = fmaxf(v0, v1);
  #pragma unroll
  for (int off = 1; off < 64; off <<= 1) mx = fmaxf(mx, __shfl_xor(mx, off));
  float sum = __expf(v0 - mx) + __expf(v1 - mx);
  #pragma unroll
  for (int off = 1; off < 64; off <<= 1) sum += __shfl_xor(sum, off);
  float lse = mx + __logf(sum);
  float2 o = make_float2(v0 - lse, v1 - lse);
  __builtin_nontemporal_store(o.x, &out[(size_t)node * 128 + lane * 2]);
  __builtin_nontemporal_store(o.y, &out[(size_t)node * 128 + lane * 2 + 1]);
}

// ---------------- host ----------------
extern "C" void kernel_launch(void* const* d_in, const int* in_sizes, int n_in,
                              void* d_out, int out_size, void* d_ws, size_t ws_size,
                              hipStream_t stream) {
  const float* x    = (const float*)d_in[0];
  const void*  ei   = d_in[1];
  const float* W1   = (const float*)d_in[2];
  const float* aS1  = (const float*)d_in[3];
  const float* aD1  = (const float*)d_in[4];
  const float* b1   = (const float*)d_in[5];
  const float* W2   = (const float*)d_in[6];
  const float* aS2  = (const float*)d_in[7];
  const float* aD2  = (const float*)d_in[8];
  const float* b2   = (const float*)d_in[9];
  float* out = (float*)d_out;

  char* ws = (char*)d_ws;
  unsigned char* h1q = (unsigned char*)ws; ws += (size_t)NN * 256;   // int8 h1 (offset-128)
  __half* h2   = (__half*)ws;          ws += (size_t)NN * 128 * 2;   // fp16 h2
  __half* hmid = (__half*)ws;          ws += (size_t)NN * 256 * 2;   // ELU(agg1) fp16
  _Float16* W1p = (_Float16*)ws;       ws += (size_t)65536 * 2;      // packed B frags
  _Float16* W2p = (_Float16*)ws;       ws += (size_t)32768 * 2;
  _Float16* Wa1p = (_Float16*)ws;      ws += (size_t)4096 * 2;
  _Float16* Wa2p = (_Float16*)ws;      ws += (size_t)4096 * 2;
  float* alS  = (float*)ws;            ws += (size_t)NN * 8 * 4;
  float* alD  = (float*)ws;            ws += (size_t)NN * 8 * 4;
  int* counts = (int*)ws;              ws += (size_t)NN * 4;
  int* rs     = (int*)ws;              ws += (size_t)(NN + 1) * 4;
  int* bsums  = (int*)ws;              ws += (size_t)256 * 4;
  int* ssrc   = (int*)ws;              ws += (size_t)NE * 4;
  int* flag   = (int*)ws;              ws += 256;

  const int NB = (NN + 255) / 256;

  // ---- CSR build ----
  detect_i64_kernel<<<1, 64, 0, stream>>>((const unsigned*)ei, flag);
  hipMemsetAsync(counts, 0, (size_t)NN * 4, stream);
  count_kernel<<<(NE + 255) / 256, 256, 0, stream>>>(ei, flag, counts);
  scan1_kernel<<<NB, 256, 0, stream>>>(counts, bsums);
  scan2_kernel<<<1, 256, 0, stream>>>(bsums, NB);
  scan3_kernel<<<NB, 256, 0, stream>>>(counts, bsums, rs);
  hipMemsetAsync(counts, 0, (size_t)NN * 4, stream);
  scatter_kernel<<<(NE + 255) / 256, 256, 0, stream>>>(ei, flag, rs, counts, ssrc);

  // ---- weight prep (fused, packed fragments) ----
  prep_kernel<<<(106496 + 255) / 256, 256, 0, stream>>>(W1, W2, aS1, aD1, aS2, aD2,
                                                        W1p, W2p, Wa1p, Wa2p);

  const int ngrid = (NN + 63) / 64;  // 782
  // ---- layer 1 ----
  gemm_mfma<256, 2, false, true><<<ngrid, 512, 0, stream>>>(x, W1p, Wa1p, h1q, alS, alD, NN);
  agg1_kernel<<<(NN + 3) / 4, 256, 0, stream>>>(h1q, alS, alD, rs, ssrc, b1, hmid);

  // ---- layer 2 ----
  gemm_mfma<128, 1, true, false><<<ngrid, 512, 0, stream>>>(hmid, W2p, Wa2p, h2, alS, alD, NN);
  agg2_kernel<<<(NN + 3) / 4, 256, 0, stream>>>(h2, alS, alD, rs, ssrc, b2, out);
}